// Round 7
// baseline (3906.808 us; speedup 1.0000x reference)
//
#include <hip/hip_runtime.h>

// RecurrentTransformerEncoder on MI355X — round 7: barrier-free wave-level
// GEMM (direct global->VGPR MFMA fragments, 2-deep register pipeline) for
// the small sequential phase-2 GEMMs; LDS-staged GEMM kept for phase 1.
// B=64, T=16, SEG=50, E=D=512, H=8, DH=64, F=2048.

#define NB   64
#define NT   16
#define SEGL 50
#define DMODEL 512
#define DFF  2048
#define NHEAD 8
#define DHEAD 64

typedef unsigned short ushort_t;
typedef __attribute__((ext_vector_type(8))) short bfrag;   // 8 bf16 (4 VGPRs)
typedef __attribute__((ext_vector_type(4))) float ffrag;   // 4 fp32 acc

__device__ __forceinline__ ushort_t f2b(float x) {
    union { float f; unsigned u; } c; c.f = x;
    unsigned r = c.u + 0x7fffu + ((c.u >> 16) & 1u);
    return (ushort_t)(r >> 16);
}

#define GLOAD_LDS16(g, l) __builtin_amdgcn_global_load_lds( \
    (const __attribute__((address_space(1))) void*)(g),      \
    (__attribute__((address_space(3))) void*)(l), 16, 0, 0)

// ---------------------------------------------------------------------------
// MFMA GEMM (phase-1, LDS-staged, BK=64 dbuf): C = relu?(A @ Bt^T), bf16.
// A rows remapped: row m at A + (m/agrp)*astride + (m%agrp)*K.
// ---------------------------------------------------------------------------
template<int BM, int BN, int WROWS, int WCOLS>
__global__ __launch_bounds__(256) void mfma_gemm(
    const ushort_t* __restrict__ A, int agrp, long long astride,
    const ushort_t* __restrict__ Bt, ushort_t* __restrict__ C,
    int M, int N, int K, int relu)
{
    constexpr int WM = BM / WROWS, WN = BN / WCOLS;
    constexpr int SM = WM / 16, SN = WN / 16;
    constexpr int NSUBA = BM / 16, NSUBB = BN / 16;
    constexpr int NSUB = NSUBA + NSUBB;
    constexpr int NINST = NSUB * 2;
    constexpr int IPW = NINST / 4;
    constexpr int BUFS = NSUB * 1024;
    constexpr int EST = WN + 8;
    constexpr int LDS_KLOOP = 2 * BUFS;
    constexpr int LDS_EPI   = 4 * WM * EST;
    constexpr int LDS_SZ = LDS_KLOOP > LDS_EPI ? LDS_KLOOP : LDS_EPI;
    __shared__ ushort_t lds[LDS_SZ];

    const int tid = threadIdx.x;
    const int wave = tid >> 6, lane = tid & 63;
    const int wrow = wave / WCOLS, wcol = wave % WCOLS;
    const int bm = blockIdx.y * BM, bn = blockIdx.x * BN;
    const int lm = lane & 15, lq = lane >> 4;

    ffrag acc[SM][SN];
#pragma unroll
    for (int i = 0; i < SM; ++i)
#pragma unroll
        for (int j = 0; j < SN; ++j) acc[i][j] = (ffrag){0.f, 0.f, 0.f, 0.f};

    const ushort_t* gptr[IPW];
    int loff[IPW];
#pragma unroll
    for (int e = 0; e < IPW; ++e) {
        int g = wave * IPW + e;
        int s = g >> 1, h = g & 1;
        if (s < NSUBA) {
            int m = bm + s * 16 + lm;
            gptr[e] = A + (long long)(m / agrp) * astride
                        + (long long)(m % agrp) * K + h * 32 + lq * 8;
        } else {
            int n = bn + (s - NSUBA) * 16 + lm;
            gptr[e] = Bt + (long long)n * K + h * 32 + lq * 8;
        }
        loff[e] = s * 1024 + h * 512;
    }

#pragma unroll
    for (int e = 0; e < IPW; ++e)
        GLOAD_LDS16(gptr[e], &lds[loff[e]]);

    const int nk = K >> 6;
    for (int kk = 0; kk < nk; ++kk) {
        __syncthreads();
        if (kk + 1 < nk) {
            const int koff = (kk + 1) << 6;
            const int nb = (kk + 1) & 1;
#pragma unroll
            for (int e = 0; e < IPW; ++e)
                GLOAD_LDS16(gptr[e] + koff, &lds[nb * BUFS + loff[e]]);
        }
        const ushort_t* lb = &lds[(kk & 1) * BUFS];
#pragma unroll
        for (int h = 0; h < 2; ++h) {
            bfrag af[SM], bfg[SN];
#pragma unroll
            for (int i = 0; i < SM; ++i)
                af[i] = *(const bfrag*)&lb[(wrow * SM + i) * 1024 + h * 512 + lane * 8];
#pragma unroll
            for (int j = 0; j < SN; ++j)
                bfg[j] = *(const bfrag*)&lb[(NSUBA + wcol * SN + j) * 1024 + h * 512 + lane * 8];
#pragma unroll
            for (int i = 0; i < SM; ++i)
#pragma unroll
                for (int j = 0; j < SN; ++j)
                    acc[i][j] = __builtin_amdgcn_mfma_f32_16x16x32_bf16(
                        af[i], bfg[j], acc[i][j], 0, 0, 0);
        }
    }

    __syncthreads();
    ushort_t* ep = &lds[wave * WM * EST];
#pragma unroll
    for (int i = 0; i < SM; ++i)
#pragma unroll
        for (int j = 0; j < SN; ++j)
#pragma unroll
            for (int r = 0; r < 4; ++r) {
                int row = i * 16 + lq * 4 + r;
                int col = j * 16 + lm;
                float v = acc[i][j][r];
                if (relu) v = fmaxf(v, 0.f);
                ep[row * EST + col] = f2b(v);
            }
    constexpr int CPR = WN / 8;
    constexpr int RPI = 64 / CPR;
    const int lrow = lane / CPR, lcol = (lane % CPR) * 8;
#pragma unroll
    for (int it = 0; it < WM / RPI; ++it) {
        int row = it * RPI + lrow;
        uint4 v = *(const uint4*)&ep[row * EST + lcol];
        long long grow = bm + wrow * WM + row;
        int gcol = bn + wcol * WN + lcol;
        *(uint4*)&C[grow * N + gcol] = v;
    }
}

// ---------------------------------------------------------------------------
// Wave GEMM (phase-2, barrier-free): 4 waves/block (2x2), each wave computes
// a (SM*16)x(SN*16) tile loading its MFMA fragments DIRECTLY from global
// (per-lane global_load_dwordx4 in fragment layout: row=lane&15, k=(lane>>4)*8).
// 2-deep register pipeline; no __syncthreads -> compiler emits per-use
// vmcnt(N) waits, loads overlap MFMA. Operands are L2/L3-resident.
// ---------------------------------------------------------------------------
template<int SM, int SN>
__global__ __launch_bounds__(256) void wave_gemm(
    const ushort_t* __restrict__ A, int agrp, long long astride,
    const ushort_t* __restrict__ Bt, ushort_t* __restrict__ C,
    int M, int N, int K, int relu)
{
    constexpr int WM = SM * 16, WN = SN * 16;
    constexpr int EST = WN + 8;
    __shared__ ushort_t ep[4][WM][EST];
    const int tid = threadIdx.x;
    const int wave = tid >> 6, lane = tid & 63;
    const int wrow = wave >> 1, wcol = wave & 1;
    const int lm = lane & 15, lq = lane >> 4;
    const int bm = blockIdx.y * (2 * WM) + wrow * WM;
    const int bn = blockIdx.x * (2 * WN) + wcol * WN;

    const ushort_t* ap[SM];
    const ushort_t* bp[SN];
#pragma unroll
    for (int i = 0; i < SM; ++i) {
        int m = bm + i * 16 + lm;
        ap[i] = A + (long long)(m / agrp) * astride + (long long)(m % agrp) * K + lq * 8;
    }
#pragma unroll
    for (int j = 0; j < SN; ++j) {
        int n = bn + j * 16 + lm;
        bp[j] = Bt + (long long)n * K + lq * 8;
    }

    ffrag acc[SM][SN];
#pragma unroll
    for (int i = 0; i < SM; ++i)
#pragma unroll
        for (int j = 0; j < SN; ++j) acc[i][j] = (ffrag){0.f, 0.f, 0.f, 0.f};

    bfrag a0[SM], b0[SN], a1[SM], b1[SN];
#pragma unroll
    for (int i = 0; i < SM; ++i) a0[i] = *(const bfrag*)(ap[i]);
#pragma unroll
    for (int j = 0; j < SN; ++j) b0[j] = *(const bfrag*)(bp[j]);

    const int nk = K >> 5;          // K/32, always even here
    for (int kk = 0; kk < nk; kk += 2) {
        const int k1 = (kk + 1) << 5;
#pragma unroll
        for (int i = 0; i < SM; ++i) a1[i] = *(const bfrag*)(ap[i] + k1);
#pragma unroll
        for (int j = 0; j < SN; ++j) b1[j] = *(const bfrag*)(bp[j] + k1);
#pragma unroll
        for (int i = 0; i < SM; ++i)
#pragma unroll
            for (int j = 0; j < SN; ++j)
                acc[i][j] = __builtin_amdgcn_mfma_f32_16x16x32_bf16(
                    a0[i], b0[j], acc[i][j], 0, 0, 0);
        if (kk + 2 < nk) {
            const int k2 = (kk + 2) << 5;
#pragma unroll
            for (int i = 0; i < SM; ++i) a0[i] = *(const bfrag*)(ap[i] + k2);
#pragma unroll
            for (int j = 0; j < SN; ++j) b0[j] = *(const bfrag*)(bp[j] + k2);
        }
#pragma unroll
        for (int i = 0; i < SM; ++i)
#pragma unroll
            for (int j = 0; j < SN; ++j)
                acc[i][j] = __builtin_amdgcn_mfma_f32_16x16x32_bf16(
                    a1[i], b1[j], acc[i][j], 0, 0, 0);
    }

    // epilogue: per-wave LDS region (in-wave DS ordering; no barrier)
#pragma unroll
    for (int i = 0; i < SM; ++i)
#pragma unroll
        for (int j = 0; j < SN; ++j)
#pragma unroll
            for (int r = 0; r < 4; ++r) {
                float v = acc[i][j][r];
                if (relu) v = fmaxf(v, 0.f);
                ep[wave][i * 16 + lq * 4 + r][j * 16 + lm] = f2b(v);
            }
    constexpr int CPR = WN / 8;          // uint4 chunks per row
    constexpr int RPI = 64 / CPR;        // rows per iteration
    const int lrow = lane / CPR, lcol = (lane % CPR) * 8;
#pragma unroll
    for (int it = 0; it < WM / RPI; ++it) {
        int row = it * RPI + lrow;
        uint4 v = *(const uint4*)&ep[wave][row][lcol];
        *(uint4*)&C[(long long)(bm + row) * N + bn + lcol] = v;
    }
}

// ---------------------------------------------------------------------------
__global__ __launch_bounds__(256) void wtrans_k(
    const float* __restrict__ W, ushort_t* __restrict__ Wt, int K, int N)
{
    __shared__ float t[32][33];
    const int bk = blockIdx.y * 32, bn = blockIdx.x * 32;
    const int tx = threadIdx.x & 31, ty = threadIdx.x >> 5;
    for (int i = ty; i < 32; i += 8)
        t[i][tx] = W[(long long)(bk + i) * N + bn + tx];
    __syncthreads();
    for (int i = ty; i < 32; i += 8)
        Wt[(long long)(bn + i) * K + bk + tx] = f2b(t[tx][i]);
}

__global__ __launch_bounds__(256) void cvt_k(
    const float* __restrict__ in, ushort_t* __restrict__ out, long long n)
{
    long long i = ((long long)blockIdx.x * 256 + threadIdx.x) * 8;
    if (i >= n) return;
    float4 a = *(const float4*)(in + i);
    float4 b = *(const float4*)(in + i + 4);
    ushort_t o[8] = {f2b(a.x), f2b(a.y), f2b(a.z), f2b(a.w),
                     f2b(b.x), f2b(b.y), f2b(b.z), f2b(b.w)};
    *(uint4*)(out + i) = *(const uint4*)o;
}

// ---------------------------------------------------------------------------
// MFMA attention, one (sequence n, head h) per block. S=50->64 pad, D=64.
// ---------------------------------------------------------------------------
__global__ __launch_bounds__(256) void attn_mfma_k(
    const ushort_t* __restrict__ Q, long long qns, long long qrs,
    const ushort_t* __restrict__ K, const ushort_t* __restrict__ V,
    long long kns, long long kvrs,
    ushort_t* __restrict__ O,
    const int* __restrict__ lens, int G, int t0)
{
    __shared__ ushort_t qs[64][72];   // Q, then P
    __shared__ ushort_t ks[64][72];
    __shared__ ushort_t vt[64][72];   // V^T
    const int n = blockIdx.x >> 3, h = blockIdx.x & 7;
    const int tid = threadIdx.x;
    const int wave = tid >> 6, lane = tid & 63;
    const int lm = lane & 15, lq = lane >> 4;
    int len = SEGL;
    if (lens) {
        int b = n / G, t = t0 + (n % G);
        len = lens[b * NT + t];
        if (len > SEGL) len = SEGL;
    }
    {
        uint4 z = {0, 0, 0, 0};
        uint4* vz = (uint4*)&vt[0][0];
        for (int i = tid; i < 64 * 72 / 8; i += 256) vz[i] = z;
    }
    __syncthreads();
    for (int idx = tid; idx < SEGL * 8; idx += 256) {
        int s = idx >> 3, d8 = (idx & 7) << 3;
        const ushort_t* qp = Q + (long long)n * qns + (long long)s * qrs + h * DHEAD + d8;
        const ushort_t* kp = K + (long long)n * kns + (long long)s * kvrs + h * DHEAD + d8;
        const ushort_t* vp = V + (long long)n * kns + (long long)s * kvrs + h * DHEAD + d8;
        *(uint4*)&qs[s][d8] = *(const uint4*)qp;
        *(uint4*)&ks[s][d8] = *(const uint4*)kp;
        uint4 v4 = *(const uint4*)vp;
        const ushort_t* vv = (const ushort_t*)&v4;
#pragma unroll
        for (int u = 0; u < 8; ++u) vt[d8 + u][s] = vv[u];
    }
    __syncthreads();

    ffrag sc[4];
#pragma unroll
    for (int nt = 0; nt < 4; ++nt) sc[nt] = (ffrag){0.f, 0.f, 0.f, 0.f};
#pragma unroll
    for (int kt = 0; kt < 2; ++kt) {
        bfrag a = *(const bfrag*)&qs[wave * 16 + lm][kt * 32 + lq * 8];
#pragma unroll
        for (int nt = 0; nt < 4; ++nt) {
            bfrag b = *(const bfrag*)&ks[nt * 16 + lm][kt * 32 + lq * 8];
            sc[nt] = __builtin_amdgcn_mfma_f32_16x16x32_bf16(a, b, sc[nt], 0, 0, 0);
        }
    }
    __syncthreads();

#pragma unroll
    for (int r = 0; r < 4; ++r) {
        float x[4];
        float mx = -1e30f;
#pragma unroll
        for (int nt = 0; nt < 4; ++nt) {
            int col = nt * 16 + lm;
            x[nt] = (col < len) ? sc[nt][r] * 0.125f : -1e9f;
            mx = fmaxf(mx, x[nt]);
        }
        for (int off = 8; off; off >>= 1) mx = fmaxf(mx, __shfl_xor(mx, off));
        float e[4], se = 0.f;
#pragma unroll
        for (int nt = 0; nt < 4; ++nt) { e[nt] = __expf(x[nt] - mx); se += e[nt]; }
        for (int off = 8; off; off >>= 1) se += __shfl_xor(se, off);
        float inv = 1.f / se;
        int row = wave * 16 + lq * 4 + r;
#pragma unroll
        for (int nt = 0; nt < 4; ++nt)
            qs[row][nt * 16 + lm] = f2b(e[nt] * inv);
    }
    __syncthreads();

    ffrag oc[4];
#pragma unroll
    for (int dt = 0; dt < 4; ++dt) oc[dt] = (ffrag){0.f, 0.f, 0.f, 0.f};
#pragma unroll
    for (int kt = 0; kt < 2; ++kt) {
        bfrag a = *(const bfrag*)&qs[wave * 16 + lm][kt * 32 + lq * 8];
#pragma unroll
        for (int dt = 0; dt < 4; ++dt) {
            bfrag b = *(const bfrag*)&vt[dt * 16 + lm][kt * 32 + lq * 8];
            oc[dt] = __builtin_amdgcn_mfma_f32_16x16x32_bf16(a, b, oc[dt], 0, 0, 0);
        }
    }
#pragma unroll
    for (int r = 0; r < 4; ++r) {
        int i = wave * 16 + lq * 4 + r;
        if (i < SEGL) {
            ushort_t* op = O + (long long)(n * SEGL + i) * DMODEL + h * DHEAD + lm;
#pragma unroll
            for (int dt = 0; dt < 4; ++dt)
                op[dt * 16] = f2b(oc[dt][r]);
        }
    }
}

// ---------------------------------------------------------------------------
// out = LN(a + b)*gamma + beta, rows of 512, bf16 in, bf16/fp32 out.
// ---------------------------------------------------------------------------
template<bool OUTF32>
__global__ __launch_bounds__(256) void add_ln_k(
    const ushort_t* __restrict__ A, int agrp, long long astride,
    const ushort_t* __restrict__ Bv,
    const float* __restrict__ gamma, const float* __restrict__ beta,
    void* __restrict__ O, int ogrp, long long ostride, int M)
{
    const int wave = threadIdx.x >> 6, lane = threadIdx.x & 63;
    const int r = blockIdx.x * 4 + wave;
    if (r >= M) return;
    const ushort_t* a = A + (long long)(r / agrp) * astride + (long long)(r % agrp) * DMODEL;
    const ushort_t* b = Bv + (long long)r * DMODEL;
    float x[8];
    {
        uint4 a4 = *(const uint4*)(a + lane * 8);
        uint4 b4 = *(const uint4*)(b + lane * 8);
        const unsigned* aa = (const unsigned*)&a4;
        const unsigned* bb = (const unsigned*)&b4;
#pragma unroll
        for (int c = 0; c < 4; ++c) {
            union { unsigned u; float f; } alo, ahi, blo, bhi;
            alo.u = aa[c] << 16; ahi.u = aa[c] & 0xffff0000u;
            blo.u = bb[c] << 16; bhi.u = bb[c] & 0xffff0000u;
            x[2 * c]     = alo.f + blo.f;
            x[2 * c + 1] = ahi.f + bhi.f;
        }
    }
    float s = 0.f, s2 = 0.f;
#pragma unroll
    for (int i = 0; i < 8; ++i) { s += x[i]; s2 = fmaf(x[i], x[i], s2); }
    for (int off = 32; off; off >>= 1) {
        s += __shfl_xor(s, off);
        s2 += __shfl_xor(s2, off);
    }
    const float mean = s * (1.f / DMODEL);
    const float var = s2 * (1.f / DMODEL) - mean * mean;
    const float inv = rsqrtf(var + 1e-5f);
    float4 g0 = *(const float4*)(gamma + lane * 8);
    float4 g1 = *(const float4*)(gamma + lane * 8 + 4);
    float4 be0 = *(const float4*)(beta + lane * 8);
    float4 be1 = *(const float4*)(beta + lane * 8 + 4);
    float y[8];
    y[0] = (x[0] - mean) * inv * g0.x + be0.x;
    y[1] = (x[1] - mean) * inv * g0.y + be0.y;
    y[2] = (x[2] - mean) * inv * g0.z + be0.z;
    y[3] = (x[3] - mean) * inv * g0.w + be0.w;
    y[4] = (x[4] - mean) * inv * g1.x + be1.x;
    y[5] = (x[5] - mean) * inv * g1.y + be1.y;
    y[6] = (x[6] - mean) * inv * g1.z + be1.z;
    y[7] = (x[7] - mean) * inv * g1.w + be1.w;
    if (OUTF32) {
        float* o = (float*)O + (long long)(r / ogrp) * ostride + (long long)(r % ogrp) * DMODEL;
        *(float4*)(o + lane * 8) = *(float4*)&y[0];
        *(float4*)(o + lane * 8 + 4) = *(float4*)&y[4];
    } else {
        ushort_t* o = (ushort_t*)O + (long long)(r / ogrp) * ostride + (long long)(r % ogrp) * DMODEL;
        ushort_t ob[8];
#pragma unroll
        for (int i = 0; i < 8; ++i) ob[i] = f2b(y[i]);
        *(uint4*)(o + lane * 8) = *(const uint4*)ob;
    }
}

__global__ void lens_k(const int* __restrict__ ends, int* __restrict__ lens)
{
    int i = blockIdx.x * 256 + threadIdx.x;
    if (i >= NB * NT) return;
    int t = i & (NT - 1);
    int prev = t ? ends[i - 1] : 0;
    int l = ends[i] - prev;
    if (l > SEGL) l = SEGL;
    lens[i] = l;
}

// ---------------------------------------------------------------------------
extern "C" void kernel_launch(void* const* d_in, const int* in_sizes, int n_in,
                              void* d_out, int out_size, void* d_ws, size_t ws_size,
                              hipStream_t stream)
{
    const float* seqs = (const float*)d_in[0];
    const int*   ends = (const int*)d_in[1];
    const float* eG1 = (const float*)d_in[7],  *eB1 = (const float*)d_in[8];
    const float* eG2 = (const float*)d_in[11], *eB2 = (const float*)d_in[12];
    const float* cG1 = (const float*)d_in[17], *cB1 = (const float*)d_in[18];
    const float* cG2 = (const float*)d_in[21], *cB2 = (const float*)d_in[22];
    float* out = (float*)d_out;

    const int G = (ws_size >= (size_t)470000000) ? 8 : 4;
    const long long CH = 1638400LL * G;

    ushort_t* ws = (ushort_t*)d_ws;
    const long long SEQROW = (long long)NT * SEGL * DMODEL;    // 409600
    ushort_t* SEQB = ws;
    ushort_t* WT   = SEQB + 26214400LL;
    ushort_t* ENC  = WT   + 6553600LL;
    ushort_t* BUF0 = ENC  + 26214400LL;
    ushort_t* QKV  = BUF0 + CH;
    ushort_t* BUF4 = QKV  + 3 * CH;
    ushort_t* BUF1 = BUF4 + CH;
    ushort_t* BUF2 = BUF1 + CH;
    ushort_t* MID  = BUF2 + CH;
    ushort_t* OUTB = MID  + 4 * CH;
    ushort_t* QALL = OUTB + 1638400LL;
    int*      lens = (int*)(QALL + 24576000LL);

    const ushort_t* eWinT = WT + 0;
    const ushort_t* WQKVe = WT + 262144;      // 1536 x 512
    const ushort_t* eWoT  = WT + 1048576;
    const ushort_t* eF1T  = WT + 1310720;     // 2048 x 512
    const ushort_t* eF2T  = WT + 2359296;     // 512 x 2048
    const ushort_t* cWqT  = WT + 3407872;
    const ushort_t* cKV   = WT + 3670016;     // 1024 x 512
    const ushort_t* cWoT  = WT + 4194304;
    const ushort_t* cF1T  = WT + 4456448;
    const ushort_t* cF2T  = WT + 5505024;

    struct WMap { int src; long long dst; int K, N; };
    const WMap wm[13] = {
        {2,  0,       512, 512},
        {3,  262144,  512, 512},
        {4,  524288,  512, 512},
        {5,  786432,  512, 512},
        {6,  1048576, 512, 512},
        {9,  1310720, 512, 2048},
        {10, 2359296, 2048, 512},
        {13, 3407872, 512, 512},
        {14, 3670016, 512, 512},
        {15, 3932160, 512, 512},
        {16, 4194304, 512, 512},
        {19, 4456448, 512, 2048},
        {20, 5505024, 2048, 512},
    };

    cvt_k<<<12800, 256, 0, stream>>>(seqs, SEQB, 26214400LL);
    for (int w = 0; w < 13; ++w) {
        dim3 g(wm[w].N / 32, wm[w].K / 32);
        wtrans_k<<<g, 256, 0, stream>>>((const float*)d_in[wm[w].src],
                                        WT + wm[w].dst, wm[w].K, wm[w].N);
    }
    lens_k<<<4, 256, 0, stream>>>(ends, lens);

    auto gemmL = [&](const ushort_t* A, int agrp, long long astr, const ushort_t* Bt,
                     ushort_t* C, int M, int N, int K, int relu) {
        dim3 g(N / 128, M / 128);
        mfma_gemm<128, 128, 2, 2><<<g, 256, 0, stream>>>(A, agrp, astr, Bt, C, M, N, K, relu);
    };
    // barrier-free wave GEMM for the small sequential GEMMs (block tile 64x64)
    auto gemmW = [&](const ushort_t* A, int agrp, long long astr, const ushort_t* Bt,
                     ushort_t* C, int M, int N, int K, int relu) {
        dim3 g(N / 64, M / 64);
        wave_gemm<2, 2><<<g, 256, 0, stream>>>(A, agrp, astr, Bt, C, M, N, K, relu);
    };

    // ---------------- Phase 1: all encoders, chunks of G segments ----------
    const int Mc = NB * G * SEGL;
    for (int c = 0; c < NT / G; ++c) {
        const int t0 = c * G;
        const ushort_t* Abase = SEQB + (long long)t0 * SEGL * DMODEL;
        ushort_t* ENCc = ENC + (long long)t0 * SEGL * DMODEL;
        gemmL(Abase, G * SEGL, SEQROW, eWinT, BUF0, Mc, 512, 512, 0);
        gemmL(BUF0, Mc, 0, WQKVe, QKV, Mc, 1536, 512, 0);
        attn_mfma_k<<<NB * G * NHEAD, 256, 0, stream>>>(
            QKV, 50LL * 1536, 1536, QKV + 512, QKV + 1024, 50LL * 1536, 1536,
            BUF4, lens, G, t0);
        gemmL(BUF4, Mc, 0, eWoT, BUF1, Mc, 512, 512, 0);
        add_ln_k<false><<<Mc / 4, 256, 0, stream>>>(BUF0, Mc, 0, BUF1, eG1, eB1,
                                                    BUF2, Mc, 0, Mc);
        gemmL(BUF2, Mc, 0, eF1T, MID, Mc, 2048, 512, 1);
        gemmL(MID, Mc, 0, eF2T, BUF1, Mc, 512, 2048, 0);
        add_ln_k<false><<<Mc / 4, 256, 0, stream>>>(BUF2, Mc, 0, BUF1, eG2, eB2,
                                                    ENCc, G * SEGL, SEQROW, Mc);
    }

    // Batched Q projections for ALL phase-2 steps
    gemmL(ENC + 25600, 750, SEQROW, cWqT, QALL, 48000, 512, 512, 0);

    // ---------------- Phase 2: 15 sequential connection steps ----------------
    const int Ms = NB * SEGL;   // 3200
    for (int t = 1; t < NT; ++t) {
        const ushort_t* currA = ENC + (long long)t * SEGL * DMODEL;
        const ushort_t* prevA; int pg; long long ps;
        if (t == 1) { prevA = ENC;  pg = SEGL; ps = SEQROW; }
        else        { prevA = OUTB; pg = Ms;   ps = 0; }
        gemmW(prevA, pg, ps, cKV, QKV, Ms, 1024, 512, 0);          // fused KV
        attn_mfma_k<<<NB * NHEAD, 256, 0, stream>>>(
            QALL + (long long)(t - 1) * 25600, 750LL * 512, 512,
            QKV, QKV + 512, 50LL * 1024, 1024,
            BUF4, nullptr, 1, 0);
        gemmW(BUF4, Ms, 0, cWoT, BUF0, Ms, 512, 512, 0);
        add_ln_k<false><<<Ms / 4, 256, 0, stream>>>(currA, SEGL, SEQROW, BUF0, cG1, cB1,
                                                    BUF2, Ms, 0, Ms);
        gemmW(BUF2, Ms, 0, cF1T, MID, Ms, 2048, 512, 1);
        gemmW(MID, Ms, 0, cF2T, BUF0, Ms, 512, 2048, 0);
        if (t == NT - 1)
            add_ln_k<true><<<Ms / 4, 256, 0, stream>>>(BUF2, Ms, 0, BUF0, cG2, cB2,
                                                       out, Ms, 0, Ms);
        else
            add_ln_k<false><<<Ms / 4, 256, 0, stream>>>(BUF2, Ms, 0, BUF0, cG2, cB2,
                                                        OUTB, Ms, 0, Ms);
    }
}

// Round 8
// 2766.592 us; speedup vs baseline: 1.4121x; 1.4121x over previous
//
#include <hip/hip_runtime.h>

// RecurrentTransformerEncoder on MI355X — round 8: revert to LDS-staged GEMM
// everywhere (r7 wave_gemm failed); phase-2 uses 64x64 tiles (2x block count,
// ~5 blocks/CU) and a fused KV-projection+cross-attention kernel.
// B=64, T=16, SEG=50, E=D=512, H=8, DH=64, F=2048.

#define NB   64
#define NT   16
#define SEGL 50
#define DMODEL 512
#define DFF  2048
#define NHEAD 8
#define DHEAD 64

typedef unsigned short ushort_t;
typedef __attribute__((ext_vector_type(8))) short bfrag;   // 8 bf16 (4 VGPRs)
typedef __attribute__((ext_vector_type(4))) float ffrag;   // 4 fp32 acc

__device__ __forceinline__ ushort_t f2b(float x) {
    union { float f; unsigned u; } c; c.f = x;
    unsigned r = c.u + 0x7fffu + ((c.u >> 16) & 1u);
    return (ushort_t)(r >> 16);
}

#define GLOAD_LDS16(g, l) __builtin_amdgcn_global_load_lds( \
    (const __attribute__((address_space(1))) void*)(g),      \
    (__attribute__((address_space(3))) void*)(l), 16, 0, 0)

// ---------------------------------------------------------------------------
// MFMA GEMM (LDS-staged, BK=64 dbuf): C = relu?(A @ Bt^T), bf16.
// A rows remapped: row m at A + (m/agrp)*astride + (m%agrp)*K.
// ---------------------------------------------------------------------------
template<int BM, int BN, int WROWS, int WCOLS>
__global__ __launch_bounds__(256) void mfma_gemm(
    const ushort_t* __restrict__ A, int agrp, long long astride,
    const ushort_t* __restrict__ Bt, ushort_t* __restrict__ C,
    int M, int N, int K, int relu)
{
    constexpr int WM = BM / WROWS, WN = BN / WCOLS;
    constexpr int SM = WM / 16, SN = WN / 16;
    constexpr int NSUBA = BM / 16, NSUBB = BN / 16;
    constexpr int NSUB = NSUBA + NSUBB;
    constexpr int NINST = NSUB * 2;
    constexpr int IPW = NINST / 4;
    constexpr int BUFS = NSUB * 1024;
    constexpr int EST = WN + 8;
    constexpr int LDS_KLOOP = 2 * BUFS;
    constexpr int LDS_EPI   = 4 * WM * EST;
    constexpr int LDS_SZ = LDS_KLOOP > LDS_EPI ? LDS_KLOOP : LDS_EPI;
    __shared__ ushort_t lds[LDS_SZ];

    const int tid = threadIdx.x;
    const int wave = tid >> 6, lane = tid & 63;
    const int wrow = wave / WCOLS, wcol = wave % WCOLS;
    const int bm = blockIdx.y * BM, bn = blockIdx.x * BN;
    const int lm = lane & 15, lq = lane >> 4;

    ffrag acc[SM][SN];
#pragma unroll
    for (int i = 0; i < SM; ++i)
#pragma unroll
        for (int j = 0; j < SN; ++j) acc[i][j] = (ffrag){0.f, 0.f, 0.f, 0.f};

    const ushort_t* gptr[IPW];
    int loff[IPW];
#pragma unroll
    for (int e = 0; e < IPW; ++e) {
        int g = wave * IPW + e;
        int s = g >> 1, h = g & 1;
        if (s < NSUBA) {
            int m = bm + s * 16 + lm;
            gptr[e] = A + (long long)(m / agrp) * astride
                        + (long long)(m % agrp) * K + h * 32 + lq * 8;
        } else {
            int n = bn + (s - NSUBA) * 16 + lm;
            gptr[e] = Bt + (long long)n * K + h * 32 + lq * 8;
        }
        loff[e] = s * 1024 + h * 512;
    }

#pragma unroll
    for (int e = 0; e < IPW; ++e)
        GLOAD_LDS16(gptr[e], &lds[loff[e]]);

    const int nk = K >> 6;
    for (int kk = 0; kk < nk; ++kk) {
        __syncthreads();
        if (kk + 1 < nk) {
            const int koff = (kk + 1) << 6;
            const int nb = (kk + 1) & 1;
#pragma unroll
            for (int e = 0; e < IPW; ++e)
                GLOAD_LDS16(gptr[e] + koff, &lds[nb * BUFS + loff[e]]);
        }
        const ushort_t* lb = &lds[(kk & 1) * BUFS];
#pragma unroll
        for (int h = 0; h < 2; ++h) {
            bfrag af[SM], bfg[SN];
#pragma unroll
            for (int i = 0; i < SM; ++i)
                af[i] = *(const bfrag*)&lb[(wrow * SM + i) * 1024 + h * 512 + lane * 8];
#pragma unroll
            for (int j = 0; j < SN; ++j)
                bfg[j] = *(const bfrag*)&lb[(NSUBA + wcol * SN + j) * 1024 + h * 512 + lane * 8];
#pragma unroll
            for (int i = 0; i < SM; ++i)
#pragma unroll
                for (int j = 0; j < SN; ++j)
                    acc[i][j] = __builtin_amdgcn_mfma_f32_16x16x32_bf16(
                        af[i], bfg[j], acc[i][j], 0, 0, 0);
        }
    }

    __syncthreads();
    ushort_t* ep = &lds[wave * WM * EST];
#pragma unroll
    for (int i = 0; i < SM; ++i)
#pragma unroll
        for (int j = 0; j < SN; ++j)
#pragma unroll
            for (int r = 0; r < 4; ++r) {
                int row = i * 16 + lq * 4 + r;
                int col = j * 16 + lm;
                float v = acc[i][j][r];
                if (relu) v = fmaxf(v, 0.f);
                ep[row * EST + col] = f2b(v);
            }
    constexpr int CPR = WN / 8;
    constexpr int RPI = 64 / CPR;
    const int lrow = lane / CPR, lcol = (lane % CPR) * 8;
#pragma unroll
    for (int it = 0; it < WM / RPI; ++it) {
        int row = it * RPI + lrow;
        uint4 v = *(const uint4*)&ep[row * EST + lcol];
        long long grow = bm + wrow * WM + row;
        int gcol = bn + wcol * WN + lcol;
        *(uint4*)&C[grow * N + gcol] = v;
    }
}

// ---------------------------------------------------------------------------
__global__ __launch_bounds__(256) void wtrans_k(
    const float* __restrict__ W, ushort_t* __restrict__ Wt, int K, int N)
{
    __shared__ float t[32][33];
    const int bk = blockIdx.y * 32, bn = blockIdx.x * 32;
    const int tx = threadIdx.x & 31, ty = threadIdx.x >> 5;
    for (int i = ty; i < 32; i += 8)
        t[i][tx] = W[(long long)(bk + i) * N + bn + tx];
    __syncthreads();
    for (int i = ty; i < 32; i += 8)
        Wt[(long long)(bn + i) * K + bk + tx] = f2b(t[tx][i]);
}

__global__ __launch_bounds__(256) void cvt_k(
    const float* __restrict__ in, ushort_t* __restrict__ out, long long n)
{
    long long i = ((long long)blockIdx.x * 256 + threadIdx.x) * 8;
    if (i >= n) return;
    float4 a = *(const float4*)(in + i);
    float4 b = *(const float4*)(in + i + 4);
    ushort_t o[8] = {f2b(a.x), f2b(a.y), f2b(a.z), f2b(a.w),
                     f2b(b.x), f2b(b.y), f2b(b.z), f2b(b.w)};
    *(uint4*)(out + i) = *(const uint4*)o;
}

// ---------------------------------------------------------------------------
// Phase-1 MFMA attention, one (sequence n, head h) per block. S=50->64, D=64.
// ---------------------------------------------------------------------------
__global__ __launch_bounds__(256) void attn_mfma_k(
    const ushort_t* __restrict__ Q, long long qns, long long qrs,
    const ushort_t* __restrict__ K, const ushort_t* __restrict__ V,
    long long kns, long long kvrs,
    ushort_t* __restrict__ O,
    const int* __restrict__ lens, int G, int t0)
{
    __shared__ ushort_t qs[64][72];   // Q, then P
    __shared__ ushort_t ks[64][72];
    __shared__ ushort_t vt[64][72];   // V^T
    const int n = blockIdx.x >> 3, h = blockIdx.x & 7;
    const int tid = threadIdx.x;
    const int wave = tid >> 6, lane = tid & 63;
    const int lm = lane & 15, lq = lane >> 4;
    int len = SEGL;
    if (lens) {
        int b = n / G, t = t0 + (n % G);
        len = lens[b * NT + t];
        if (len > SEGL) len = SEGL;
    }
    {
        uint4 z = {0, 0, 0, 0};
        uint4* vz = (uint4*)&vt[0][0];
        for (int i = tid; i < 64 * 72 / 8; i += 256) vz[i] = z;
    }
    __syncthreads();
    for (int idx = tid; idx < SEGL * 8; idx += 256) {
        int s = idx >> 3, d8 = (idx & 7) << 3;
        const ushort_t* qp = Q + (long long)n * qns + (long long)s * qrs + h * DHEAD + d8;
        const ushort_t* kp = K + (long long)n * kns + (long long)s * kvrs + h * DHEAD + d8;
        const ushort_t* vp = V + (long long)n * kns + (long long)s * kvrs + h * DHEAD + d8;
        *(uint4*)&qs[s][d8] = *(const uint4*)qp;
        *(uint4*)&ks[s][d8] = *(const uint4*)kp;
        uint4 v4 = *(const uint4*)vp;
        const ushort_t* vv = (const ushort_t*)&v4;
#pragma unroll
        for (int u = 0; u < 8; ++u) vt[d8 + u][s] = vv[u];
    }
    __syncthreads();

    ffrag sc[4];
#pragma unroll
    for (int nt = 0; nt < 4; ++nt) sc[nt] = (ffrag){0.f, 0.f, 0.f, 0.f};
#pragma unroll
    for (int kt = 0; kt < 2; ++kt) {
        bfrag a = *(const bfrag*)&qs[wave * 16 + lm][kt * 32 + lq * 8];
#pragma unroll
        for (int nt = 0; nt < 4; ++nt) {
            bfrag b = *(const bfrag*)&ks[nt * 16 + lm][kt * 32 + lq * 8];
            sc[nt] = __builtin_amdgcn_mfma_f32_16x16x32_bf16(a, b, sc[nt], 0, 0, 0);
        }
    }
    __syncthreads();

#pragma unroll
    for (int r = 0; r < 4; ++r) {
        float x[4];
        float mx = -1e30f;
#pragma unroll
        for (int nt = 0; nt < 4; ++nt) {
            int col = nt * 16 + lm;
            x[nt] = (col < len) ? sc[nt][r] * 0.125f : -1e9f;
            mx = fmaxf(mx, x[nt]);
        }
        for (int off = 8; off; off >>= 1) mx = fmaxf(mx, __shfl_xor(mx, off));
        float e[4], se = 0.f;
#pragma unroll
        for (int nt = 0; nt < 4; ++nt) { e[nt] = __expf(x[nt] - mx); se += e[nt]; }
        for (int off = 8; off; off >>= 1) se += __shfl_xor(se, off);
        float inv = 1.f / se;
        int row = wave * 16 + lq * 4 + r;
#pragma unroll
        for (int nt = 0; nt < 4; ++nt)
            qs[row][nt * 16 + lm] = f2b(e[nt] * inv);
    }
    __syncthreads();

    ffrag oc[4];
#pragma unroll
    for (int dt = 0; dt < 4; ++dt) oc[dt] = (ffrag){0.f, 0.f, 0.f, 0.f};
#pragma unroll
    for (int kt = 0; kt < 2; ++kt) {
        bfrag a = *(const bfrag*)&qs[wave * 16 + lm][kt * 32 + lq * 8];
#pragma unroll
        for (int dt = 0; dt < 4; ++dt) {
            bfrag b = *(const bfrag*)&vt[dt * 16 + lm][kt * 32 + lq * 8];
            oc[dt] = __builtin_amdgcn_mfma_f32_16x16x32_bf16(a, b, oc[dt], 0, 0, 0);
        }
    }
#pragma unroll
    for (int r = 0; r < 4; ++r) {
        int i = wave * 16 + lq * 4 + r;
        if (i < SEGL) {
            ushort_t* op = O + (long long)(n * SEGL + i) * DMODEL + h * DHEAD + lm;
#pragma unroll
            for (int dt = 0; dt < 4; ++dt)
                op[dt * 16] = f2b(oc[dt][r]);
        }
    }
}

// ---------------------------------------------------------------------------
// Phase-2 fused KV-projection + cross-attention. One (seq n, head h) block.
// K_h = prev_n @ cKV[h*64.. ]^T, V_h = prev_n @ cKV[512+h*64.. ]^T computed
// in-block via MFMA (prev staged in LDS in two 256-wide K halves; weight
// fragments read from global — same addrs across n-blocks -> L2 broadcast).
// prev rows ZEROED for s>=50 so V pads are exact 0 (NaN-safe PV).
// Then standard attn (len=50). Q from QALL (qns/qrs strides).
// ---------------------------------------------------------------------------
__global__ __launch_bounds__(256) void cross_attn_k(
    const ushort_t* __restrict__ Qp, long long qns, long long qrs,
    const ushort_t* __restrict__ Prev, int pgrp, long long pstride,
    const ushort_t* __restrict__ Wkv,   // [1024][512] bf16 (cWk^T | cWv^T)
    ushort_t* __restrict__ O)
{
    __shared__ ushort_t xp[64 * 264];   // phase A: prev half; phase B: ks|vt
    __shared__ ushort_t qs[64][72];     // Q, then P
    const int n = blockIdx.x >> 3, h = blockIdx.x & 7;
    const int tid = threadIdx.x;
    const int wave = tid >> 6, lane = tid & 63;
    const int lm = lane & 15, lq = lane >> 4;

    // load Q rows
    for (int idx = tid; idx < SEGL * 8; idx += 256) {
        int s = idx >> 3, d8 = (idx & 7) << 3;
        *(uint4*)&qs[s][d8] =
            *(const uint4*)(Qp + (long long)n * qns + (long long)s * qrs + h * DHEAD + d8);
    }

    // KV projection: wave 0/1 -> K cols 0-31/32-63; wave 2/3 -> V cols.
    const ushort_t* wbase = Wkv +
        (long long)((wave >> 1) * 512 + h * 64 + (wave & 1) * 32) * 512;
    ffrag kv[4][2];
#pragma unroll
    for (int i = 0; i < 4; ++i)
#pragma unroll
        for (int j = 0; j < 2; ++j) kv[i][j] = (ffrag){0.f, 0.f, 0.f, 0.f};

#pragma unroll
    for (int half = 0; half < 2; ++half) {
        __syncthreads();   // prior reads of xp done
        for (int idx = tid; idx < 64 * 33; idx += 256) {
            int s = idx / 33, c8 = (idx % 33) * 8;
            uint4 v = {0, 0, 0, 0};
            if (s < SEGL && c8 < 256) {
                long long r = (long long)n * SEGL + s;
                v = *(const uint4*)(Prev + (r / pgrp) * pstride
                                    + (r % pgrp) * DMODEL + half * 256 + c8);
            }
            *(uint4*)&xp[s * 264 + c8] = v;
        }
        __syncthreads();
#pragma unroll
        for (int k8 = 0; k8 < 8; ++k8) {
            const int kg = half * 256 + k8 * 32;
            bfrag bf[2], af[4];
#pragma unroll
            for (int j = 0; j < 2; ++j)
                bf[j] = *(const bfrag*)(wbase + (long long)(j * 16 + lm) * 512 + kg + lq * 8);
#pragma unroll
            for (int i = 0; i < 4; ++i)
                af[i] = *(const bfrag*)&xp[(i * 16 + lm) * 264 + k8 * 32 + lq * 8];
#pragma unroll
            for (int i = 0; i < 4; ++i)
#pragma unroll
                for (int j = 0; j < 2; ++j)
                    kv[i][j] = __builtin_amdgcn_mfma_f32_16x16x32_bf16(
                        af[i], bf[j], kv[i][j], 0, 0, 0);
        }
    }
    __syncthreads();   // all xp reads done before ks/vt overwrite
    ushort_t (*ks)[72] = (ushort_t(*)[72])&xp[0];
    ushort_t (*vt)[72] = (ushort_t(*)[72])&xp[64 * 72];
#pragma unroll
    for (int i = 0; i < 4; ++i)
#pragma unroll
        for (int j = 0; j < 2; ++j)
#pragma unroll
            for (int r = 0; r < 4; ++r) {
                int rowk = i * 16 + lq * 4 + r;
                int d = (wave & 1) * 32 + j * 16 + lm;
                ushort_t val = f2b(kv[i][j][r]);
                if (wave < 2) ks[rowk][d] = val;   // K[rowk][d]
                else          vt[d][rowk] = val;   // V^T[d][rowk]
            }
    __syncthreads();

    // QK^T
    ffrag sc[4];
#pragma unroll
    for (int nt = 0; nt < 4; ++nt) sc[nt] = (ffrag){0.f, 0.f, 0.f, 0.f};
#pragma unroll
    for (int kt = 0; kt < 2; ++kt) {
        bfrag a = *(const bfrag*)&qs[wave * 16 + lm][kt * 32 + lq * 8];
#pragma unroll
        for (int nt = 0; nt < 4; ++nt) {
            bfrag b = *(const bfrag*)&ks[nt * 16 + lm][kt * 32 + lq * 8];
            sc[nt] = __builtin_amdgcn_mfma_f32_16x16x32_bf16(a, b, sc[nt], 0, 0, 0);
        }
    }
    __syncthreads();

#pragma unroll
    for (int r = 0; r < 4; ++r) {
        float x[4];
        float mx = -1e30f;
#pragma unroll
        for (int nt = 0; nt < 4; ++nt) {
            int col = nt * 16 + lm;
            x[nt] = (col < SEGL) ? sc[nt][r] * 0.125f : -1e9f;
            mx = fmaxf(mx, x[nt]);
        }
        for (int off = 8; off; off >>= 1) mx = fmaxf(mx, __shfl_xor(mx, off));
        float e[4], se = 0.f;
#pragma unroll
        for (int nt = 0; nt < 4; ++nt) { e[nt] = __expf(x[nt] - mx); se += e[nt]; }
        for (int off = 8; off; off >>= 1) se += __shfl_xor(se, off);
        float inv = 1.f / se;
        int row = wave * 16 + lq * 4 + r;
#pragma unroll
        for (int nt = 0; nt < 4; ++nt)
            qs[row][nt * 16 + lm] = f2b(e[nt] * inv);
    }
    __syncthreads();

    // PV
    ffrag oc[4];
#pragma unroll
    for (int dt = 0; dt < 4; ++dt) oc[dt] = (ffrag){0.f, 0.f, 0.f, 0.f};
#pragma unroll
    for (int kt = 0; kt < 2; ++kt) {
        bfrag a = *(const bfrag*)&qs[wave * 16 + lm][kt * 32 + lq * 8];
#pragma unroll
        for (int dt = 0; dt < 4; ++dt) {
            bfrag b = *(const bfrag*)&vt[dt * 16 + lm][kt * 32 + lq * 8];
            oc[dt] = __builtin_amdgcn_mfma_f32_16x16x32_bf16(a, b, oc[dt], 0, 0, 0);
        }
    }
#pragma unroll
    for (int r = 0; r < 4; ++r) {
        int i = wave * 16 + lq * 4 + r;
        if (i < SEGL) {
            ushort_t* op = O + (long long)(n * SEGL + i) * DMODEL + h * DHEAD + lm;
#pragma unroll
            for (int dt = 0; dt < 4; ++dt)
                op[dt * 16] = f2b(oc[dt][r]);
        }
    }
}

// ---------------------------------------------------------------------------
// out = LN(a + b)*gamma + beta, rows of 512, bf16 in, bf16/fp32 out.
// ---------------------------------------------------------------------------
template<bool OUTF32>
__global__ __launch_bounds__(256) void add_ln_k(
    const ushort_t* __restrict__ A, int agrp, long long astride,
    const ushort_t* __restrict__ Bv,
    const float* __restrict__ gamma, const float* __restrict__ beta,
    void* __restrict__ O, int ogrp, long long ostride, int M)
{
    const int wave = threadIdx.x >> 6, lane = threadIdx.x & 63;
    const int r = blockIdx.x * 4 + wave;
    if (r >= M) return;
    const ushort_t* a = A + (long long)(r / agrp) * astride + (long long)(r % agrp) * DMODEL;
    const ushort_t* b = Bv + (long long)r * DMODEL;
    float x[8];
    {
        uint4 a4 = *(const uint4*)(a + lane * 8);
        uint4 b4 = *(const uint4*)(b + lane * 8);
        const unsigned* aa = (const unsigned*)&a4;
        const unsigned* bb = (const unsigned*)&b4;
#pragma unroll
        for (int c = 0; c < 4; ++c) {
            union { unsigned u; float f; } alo, ahi, blo, bhi;
            alo.u = aa[c] << 16; ahi.u = aa[c] & 0xffff0000u;
            blo.u = bb[c] << 16; bhi.u = bb[c] & 0xffff0000u;
            x[2 * c]     = alo.f + blo.f;
            x[2 * c + 1] = ahi.f + bhi.f;
        }
    }
    float s = 0.f, s2 = 0.f;
#pragma unroll
    for (int i = 0; i < 8; ++i) { s += x[i]; s2 = fmaf(x[i], x[i], s2); }
    for (int off = 32; off; off >>= 1) {
        s += __shfl_xor(s, off);
        s2 += __shfl_xor(s2, off);
    }
    const float mean = s * (1.f / DMODEL);
    const float var = s2 * (1.f / DMODEL) - mean * mean;
    const float inv = rsqrtf(var + 1e-5f);
    float4 g0 = *(const float4*)(gamma + lane * 8);
    float4 g1 = *(const float4*)(gamma + lane * 8 + 4);
    float4 be0 = *(const float4*)(beta + lane * 8);
    float4 be1 = *(const float4*)(beta + lane * 8 + 4);
    float y[8];
    y[0] = (x[0] - mean) * inv * g0.x + be0.x;
    y[1] = (x[1] - mean) * inv * g0.y + be0.y;
    y[2] = (x[2] - mean) * inv * g0.z + be0.z;
    y[3] = (x[3] - mean) * inv * g0.w + be0.w;
    y[4] = (x[4] - mean) * inv * g1.x + be1.x;
    y[5] = (x[5] - mean) * inv * g1.y + be1.y;
    y[6] = (x[6] - mean) * inv * g1.z + be1.z;
    y[7] = (x[7] - mean) * inv * g1.w + be1.w;
    if (OUTF32) {
        float* o = (float*)O + (long long)(r / ogrp) * ostride + (long long)(r % ogrp) * DMODEL;
        *(float4*)(o + lane * 8) = *(float4*)&y[0];
        *(float4*)(o + lane * 8 + 4) = *(float4*)&y[4];
    } else {
        ushort_t* o = (ushort_t*)O + (long long)(r / ogrp) * ostride + (long long)(r % ogrp) * DMODEL;
        ushort_t ob[8];
#pragma unroll
        for (int i = 0; i < 8; ++i) ob[i] = f2b(y[i]);
        *(uint4*)(o + lane * 8) = *(const uint4*)ob;
    }
}

__global__ void lens_k(const int* __restrict__ ends, int* __restrict__ lens)
{
    int i = blockIdx.x * 256 + threadIdx.x;
    if (i >= NB * NT) return;
    int t = i & (NT - 1);
    int prev = t ? ends[i - 1] : 0;
    int l = ends[i] - prev;
    if (l > SEGL) l = SEGL;
    lens[i] = l;
}

// ---------------------------------------------------------------------------
extern "C" void kernel_launch(void* const* d_in, const int* in_sizes, int n_in,
                              void* d_out, int out_size, void* d_ws, size_t ws_size,
                              hipStream_t stream)
{
    const float* seqs = (const float*)d_in[0];
    const int*   ends = (const int*)d_in[1];
    const float* eG1 = (const float*)d_in[7],  *eB1 = (const float*)d_in[8];
    const float* eG2 = (const float*)d_in[11], *eB2 = (const float*)d_in[12];
    const float* cG1 = (const float*)d_in[17], *cB1 = (const float*)d_in[18];
    const float* cG2 = (const float*)d_in[21], *cB2 = (const float*)d_in[22];
    float* out = (float*)d_out;

    const int G = (ws_size >= (size_t)470000000) ? 8 : 4;
    const long long CH = 1638400LL * G;

    ushort_t* ws = (ushort_t*)d_ws;
    const long long SEQROW = (long long)NT * SEGL * DMODEL;    // 409600
    ushort_t* SEQB = ws;
    ushort_t* WT   = SEQB + 26214400LL;
    ushort_t* ENC  = WT   + 6553600LL;
    ushort_t* BUF0 = ENC  + 26214400LL;
    ushort_t* QKV  = BUF0 + CH;
    ushort_t* BUF4 = QKV  + 3 * CH;
    ushort_t* BUF1 = BUF4 + CH;
    ushort_t* BUF2 = BUF1 + CH;
    ushort_t* MID  = BUF2 + CH;
    ushort_t* OUTB = MID  + 4 * CH;
    ushort_t* QALL = OUTB + 1638400LL;
    int*      lens = (int*)(QALL + 24576000LL);

    const ushort_t* eWinT = WT + 0;
    const ushort_t* WQKVe = WT + 262144;      // 1536 x 512
    const ushort_t* eWoT  = WT + 1048576;
    const ushort_t* eF1T  = WT + 1310720;     // 2048 x 512
    const ushort_t* eF2T  = WT + 2359296;     // 512 x 2048
    const ushort_t* cWqT  = WT + 3407872;
    const ushort_t* cKV   = WT + 3670016;     // 1024 x 512
    const ushort_t* cWoT  = WT + 4194304;
    const ushort_t* cF1T  = WT + 4456448;
    const ushort_t* cF2T  = WT + 5505024;

    struct WMap { int src; long long dst; int K, N; };
    const WMap wm[13] = {
        {2,  0,       512, 512},
        {3,  262144,  512, 512},
        {4,  524288,  512, 512},
        {5,  786432,  512, 512},
        {6,  1048576, 512, 512},
        {9,  1310720, 512, 2048},
        {10, 2359296, 2048, 512},
        {13, 3407872, 512, 512},
        {14, 3670016, 512, 512},
        {15, 3932160, 512, 512},
        {16, 4194304, 512, 512},
        {19, 4456448, 512, 2048},
        {20, 5505024, 2048, 512},
    };

    cvt_k<<<12800, 256, 0, stream>>>(seqs, SEQB, 26214400LL);
    for (int w = 0; w < 13; ++w) {
        dim3 g(wm[w].N / 32, wm[w].K / 32);
        wtrans_k<<<g, 256, 0, stream>>>((const float*)d_in[wm[w].src],
                                        WT + wm[w].dst, wm[w].K, wm[w].N);
    }
    lens_k<<<4, 256, 0, stream>>>(ends, lens);

    auto gemmL = [&](const ushort_t* A, int agrp, long long astr, const ushort_t* Bt,
                     ushort_t* C, int M, int N, int K, int relu) {
        dim3 g(N / 128, M / 128);
        mfma_gemm<128, 128, 2, 2><<<g, 256, 0, stream>>>(A, agrp, astr, Bt, C, M, N, K, relu);
    };
    // phase-2 small GEMM: 64x64 tiles -> 2x block count, ~5 blocks/CU
    auto gemmS = [&](const ushort_t* A, int agrp, long long astr, const ushort_t* Bt,
                     ushort_t* C, int M, int N, int K, int relu) {
        dim3 g(N / 64, M / 64);
        mfma_gemm<64, 64, 2, 2><<<g, 256, 0, stream>>>(A, agrp, astr, Bt, C, M, N, K, relu);
    };

    // ---------------- Phase 1: all encoders, chunks of G segments ----------
    const int Mc = NB * G * SEGL;
    for (int c = 0; c < NT / G; ++c) {
        const int t0 = c * G;
        const ushort_t* Abase = SEQB + (long long)t0 * SEGL * DMODEL;
        ushort_t* ENCc = ENC + (long long)t0 * SEGL * DMODEL;
        gemmL(Abase, G * SEGL, SEQROW, eWinT, BUF0, Mc, 512, 512, 0);
        gemmL(BUF0, Mc, 0, WQKVe, QKV, Mc, 1536, 512, 0);
        attn_mfma_k<<<NB * G * NHEAD, 256, 0, stream>>>(
            QKV, 50LL * 1536, 1536, QKV + 512, QKV + 1024, 50LL * 1536, 1536,
            BUF4, lens, G, t0);
        gemmL(BUF4, Mc, 0, eWoT, BUF1, Mc, 512, 512, 0);
        add_ln_k<false><<<Mc / 4, 256, 0, stream>>>(BUF0, Mc, 0, BUF1, eG1, eB1,
                                                    BUF2, Mc, 0, Mc);
        gemmL(BUF2, Mc, 0, eF1T, MID, Mc, 2048, 512, 1);
        gemmL(MID, Mc, 0, eF2T, BUF1, Mc, 512, 2048, 0);
        add_ln_k<false><<<Mc / 4, 256, 0, stream>>>(BUF2, Mc, 0, BUF1, eG2, eB2,
                                                    ENCc, G * SEGL, SEQROW, Mc);
    }

    // Batched Q projections for ALL phase-2 steps
    gemmL(ENC + 25600, 750, SEQROW, cWqT, QALL, 48000, 512, 512, 0);

    // ---------------- Phase 2: 15 sequential connection steps ----------------
    const int Ms = NB * SEGL;   // 3200
    for (int t = 1; t < NT; ++t) {
        const ushort_t* currA = ENC + (long long)t * SEGL * DMODEL;
        const ushort_t* prevA; int pg; long long ps;
        if (t == 1) { prevA = ENC;  pg = SEGL; ps = SEQROW; }
        else        { prevA = OUTB; pg = Ms;   ps = 0; }
        // fused KV-projection + cross-attention
        cross_attn_k<<<NB * NHEAD, 256, 0, stream>>>(
            QALL + (long long)(t - 1) * 25600, 750LL * 512, 512,
            prevA, pg, ps, cKV, BUF4);
        gemmS(BUF4, Ms, 0, cWoT, BUF0, Ms, 512, 512, 0);
        add_ln_k<false><<<Ms / 4, 256, 0, stream>>>(currA, SEGL, SEQROW, BUF0, cG1, cB1,
                                                    BUF2, Ms, 0, Ms);
        gemmS(BUF2, Ms, 0, cF1T, MID, Ms, 2048, 512, 1);
        gemmS(MID, Ms, 0, cF2T, BUF0, Ms, 512, 2048, 0);
        if (t == NT - 1)
            add_ln_k<true><<<Ms / 4, 256, 0, stream>>>(BUF2, Ms, 0, BUF0, cG2, cB2,
                                                       out, Ms, 0, Ms);
        else
            add_ln_k<false><<<Ms / 4, 256, 0, stream>>>(BUF2, Ms, 0, BUF0, cG2, cB2,
                                                        OUTB, Ms, 0, Ms);
    }
}